// Round 1
// 435.826 us; speedup vs baseline: 1.0321x; 1.0321x over previous
//
#include <hip/hip_runtime.h>
#include <hip/hip_bf16.h>
#include <cstdint>
#include <cstddef>

#define B_ 4
#define L_ 8192
#define D_ 512
#define H_ 1024
#define NC_ 256           // chunks along L for the 3-phase scan
#define LC_ (L_ / NC_)    // 32

typedef float  f32x4 __attribute__((ext_vector_type(4)));
typedef short  s16x8 __attribute__((ext_vector_type(8)));
typedef __bf16 b16x8 __attribute__((ext_vector_type(8)));

// ---- MFMA wrapper: tolerate either builtin signature (v8i16 or v8bf16) ----
template <typename T, typename U>
__device__ inline auto mfma_sel(T a, T b, f32x4 c, U, int)
    -> decltype(__builtin_amdgcn_mfma_f32_16x16x32_bf16(a, b, c, 0, 0, 0)) {
  return __builtin_amdgcn_mfma_f32_16x16x32_bf16(a, b, c, 0, 0, 0);
}
template <typename T, typename U>
__device__ inline f32x4 mfma_sel(T a, T b, f32x4 c, U, long) {
  return __builtin_amdgcn_mfma_f32_16x16x32_bf16(
      __builtin_bit_cast(U, a), __builtin_bit_cast(U, b), c, 0, 0, 0);
}
__device__ inline f32x4 mfma_bf16_16x16x32(s16x8 a, s16x8 b, f32x4 c) {
  return mfma_sel(a, b, c, b16x8{}, 0);
}

// ---- fp32 <-> bf16 ----
__device__ inline ushort f2bf(float f) {
  uint32_t u = __builtin_bit_cast(uint32_t, f);
  uint32_t r = (u + 0x7fffu + ((u >> 16) & 1u)) >> 16;
  return (ushort)r;
}
__device__ inline float bf2f(ushort u) {
  return __builtin_bit_cast(float, (uint32_t)u << 16);
}

__global__ void cast_kernel(const float* __restrict__ in, ushort* __restrict__ out, int n4) {
  int i = blockIdx.x * blockDim.x + threadIdx.x;
  if (i >= n4) return;
  float4 f = reinterpret_cast<const float4*>(in)[i];
  ushort4 o;
  o.x = f2bf(f.x); o.y = f2bf(f.y); o.z = f2bf(f.z); o.w = f2bf(f.w);
  reinterpret_cast<ushort4*>(out)[i] = o;
}

// both weights in one launch
__global__ void cast2_kernel(const float* __restrict__ in0, ushort* __restrict__ out0, int n4_0,
                             const float* __restrict__ in1, ushort* __restrict__ out1, int n4_1) {
  int i = blockIdx.x * blockDim.x + threadIdx.x;
  const float* in; ushort* out;
  if (i < n4_0) { in = in0; out = out0; }
  else { i -= n4_0; if (i >= n4_1) return; in = in1; out = out1; }
  float4 f = reinterpret_cast<const float4*>(in)[i];
  ushort4 o;
  o.x = f2bf(f.x); o.y = f2bf(f.y); o.z = f2bf(f.z); o.w = f2bf(f.w);
  reinterpret_cast<ushort4*>(out)[i] = o;
}

#define GLDS(srcp, dstp)                                                            \
  __builtin_amdgcn_global_load_lds(                                                 \
      (const __attribute__((address_space(1))) void*)(srcp),                        \
      (__attribute__((address_space(3))) void*)(dstp), 16, 0, 0)

// barrier with full compiler memory fence (raw s_barrier; vmcnt managed manually)
#define BAR()                               \
  do {                                      \
    asm volatile("" ::: "memory");          \
    __builtin_amdgcn_s_barrier();           \
    asm volatile("" ::: "memory");          \
  } while (0)

// ---- NT GEMM: C[m][n] = sum_k A[m][k]*Bm[n][k] + bias[n]; A:MxK, Bm:NxK (row-major bf16) ----
// 256x256 tile, BK=64, 512 threads = 8 waves (2M x 4N), per-wave 128x64 output (acc[8][4]).
// Double-buffered LDS (128 KiB), counted vmcnt(8) so next tile's 8 global_load_lds stay in
// flight across the tile barrier (T3+T4). Compute split into 4 phases/tile (kh x m-half,
// 16 MFMA each) with s_setprio around the MFMA cluster (T5). LDS chunk-XOR swizzle as before
// (T2, measured 0 bank conflicts): physical 16B slot p of row r holds logical chunk p^(r&7).
// XCD-aware bijective block swizzle (T1; both grids divisible by 8).
template <bool OUT_BF16>
__global__ __launch_bounds__(512, 2)
void gemm_bt(const ushort* __restrict__ A, const ushort* __restrict__ Bm,
             const float* __restrict__ bias, void* __restrict__ Cv,
             int M, int N, int K) {
  __shared__ ushort As[2][256 * 64];
  __shared__ ushort Bs[2][256 * 64];
  const int tid  = threadIdx.x;
  const int wave = tid >> 6;
  const int lane = tid & 63;
  const int l15  = lane & 15;
  const int quad = lane >> 4;

  // XCD swizzle: dispatch index d goes to XCD d%8; give each XCD a contiguous logical chunk.
  int id = blockIdx.y * gridDim.x + blockIdx.x;
  const int nwg = gridDim.x * gridDim.y;
  id = (id & 7) * (nwg >> 3) + (id >> 3);
  const int bxi = id % gridDim.x;
  const int byi = id / gridDim.x;

  const long bm = (long)byi * 256;
  const long bn = (long)bxi * 256;
  const int  wm = (wave >> 2) * 128;   // 0 or 128
  const int  wn = (wave & 3) * 64;     // 0,64,128,192

  f32x4 acc[8][4];
#pragma unroll
  for (int i = 0; i < 8; ++i)
#pragma unroll
    for (int j = 0; j < 4; ++j) acc[i][j] = (f32x4){0.f, 0.f, 0.f, 0.f};

  // staging: instr i covers rows i*64 + wave*8 + (lane>>3); lane&7 = physical 16B slot;
  // global chunk = slot ^ (row&7) so a linear LDS write gives the swizzled layout.
  const int rl = lane >> 3;
  const int cb = (lane & 7) ^ rl;
  const ushort* gA = A  + (bm + wave * 8 + rl) * (long)K + cb * 8;
  const ushort* gB = Bm + (bn + wave * 8 + rl) * (long)K + cb * 8;
  const int lbase = wave * 8 * 64;     // ushort offset of this wave's 8-row group

  // fragment-read swizzled slot offsets (row&7 == l15&7 for all frag rows)
  const int sq0 = ((0 * 4 + quad) ^ (l15 & 7)) * 8;
  const int sq1 = ((1 * 4 + quad) ^ (l15 & 7)) * 8;
  int arow[8], brow[4];
#pragma unroll
  for (int i = 0; i < 8; ++i) arow[i] = (wm + i * 16 + l15) * 64;
#pragma unroll
  for (int j = 0; j < 4; ++j) brow[j] = (wn + j * 16 + l15) * 64;

  const int nkt = K >> 6;

  // prologue: stage tile 0 -> buf 0 (8 global_load_lds per wave)
#pragma unroll
  for (int i = 0; i < 4; ++i) {
    GLDS(gA + (long)i * 64 * K, &As[0][i * 64 * 64 + lbase]);
    GLDS(gB + (long)i * 64 * K, &Bs[0][i * 64 * 64 + lbase]);
  }

  int cur = 0;
  for (int t = 0; t < nkt; ++t) {
    if (t + 1 < nkt) {
      // prefetch tile t+1 into the other buffer. WAR is safe: buf[cur^1] was last read
      // during iter t-1, and all waves' ds_reads completed before iter t-1's trailing
      // barrier (reads are consumed by MFMAs before that barrier).
      const ushort* pa = gA + (long)(t + 1) * 64;
      const ushort* pb = gB + (long)(t + 1) * 64;
      ushort* la = &As[cur ^ 1][lbase];
      ushort* lb = &Bs[cur ^ 1][lbase];
#pragma unroll
      for (int i = 0; i < 4; ++i) {
        GLDS(pa + (long)i * 64 * K, la + i * 64 * 64);
        GLDS(pb + (long)i * 64 * K, lb + i * 64 * 64);
      }
      // counted wait: oldest 8 = tile t's loads (landed); tile t+1's 8 stay in flight.
      asm volatile("s_waitcnt vmcnt(8)" ::: "memory");
    } else {
      asm volatile("s_waitcnt vmcnt(0)" ::: "memory");
    }
    BAR();  // all waves' slices of tile t are visible in LDS

    const ushort* Ac = As[cur];
    const ushort* Bc = Bs[cur];
#pragma unroll
    for (int kh = 0; kh < 2; ++kh) {
      const int sq = kh ? sq1 : sq0;
      s16x8 bf[4], af[4];
      // phase (kh, m-half 0): read B-frags (held across both m-half phases) + low A-frags
#pragma unroll
      for (int j = 0; j < 4; ++j)
        bf[j] = *reinterpret_cast<const s16x8*>(&Bc[brow[j] + sq]);
#pragma unroll
      for (int i = 0; i < 4; ++i)
        af[i] = *reinterpret_cast<const s16x8*>(&Ac[arow[i] + sq]);
      BAR();
      __builtin_amdgcn_s_setprio(1);
#pragma unroll
      for (int i = 0; i < 4; ++i)
#pragma unroll
        for (int j = 0; j < 4; ++j)
          acc[i][j] = mfma_bf16_16x16x32(af[i], bf[j], acc[i][j]);
      __builtin_amdgcn_s_setprio(0);
      BAR();
      // phase (kh, m-half 1): high A-frags, reuse bf
#pragma unroll
      for (int i = 0; i < 4; ++i)
        af[i] = *reinterpret_cast<const s16x8*>(&Ac[arow[4 + i] + sq]);
      BAR();
      __builtin_amdgcn_s_setprio(1);
#pragma unroll
      for (int i = 0; i < 4; ++i)
#pragma unroll
        for (int j = 0; j < 4; ++j)
          acc[4 + i][j] = mfma_bf16_16x16x32(af[i], bf[j], acc[4 + i][j]);
      __builtin_amdgcn_s_setprio(0);
      BAR();
    }
    cur ^= 1;
  }

  // epilogue: C/D layout col = lane&15, row = quad*4 + reg
#pragma unroll
  for (int mi = 0; mi < 8; ++mi) {
    const long mrow = bm + wm + mi * 16 + quad * 4;
#pragma unroll
    for (int ni = 0; ni < 4; ++ni) {
      const long ncol = bn + wn + ni * 16 + l15;
      const float bv = bias[ncol];
      if (OUT_BF16) {
        ushort* cp = (ushort*)Cv + mrow * (long)N + ncol;
#pragma unroll
        for (int r = 0; r < 4; ++r) cp[(long)r * N] = f2bf(acc[mi][ni][r] + bv);
      } else {
        float* cp = (float*)Cv + mrow * (long)N + ncol;
#pragma unroll
        for (int r = 0; r < 4; ++r) cp[(long)r * N] = acc[mi][ni][r] + bv;
      }
    }
  }
}

// ---- scan helpers ----
__device__ inline float softplus_f(float x) {
  return fmaxf(x, 0.f) + __logf(1.f + __expf(-fabsf(x)));
}
__device__ inline float logaddexp_f(float a, float b) {
  float m = fmaxf(a, b);
  return m + __logf(1.f + __expf(-fabsf(a - b)));
}
// from (hidden, gate): lc = -softplus(g); v = log_z + log_tilde_h
__device__ inline void transform_f(float hd, float g, float& lc, float& v) {
  float sp = softplus_f(g);
  lc = -sp;
  float lz = g - sp;                       // -softplus(-g)
  float lth = (hd >= 0.f) ? __logf(hd + 0.5f) : (hd - softplus_f(hd));
  v = lz + lth;
}

// phase 1: per (b, chunk, h-quad) compute chunk composition (Asum, Bv) for 4 channels
__global__ void scan_phase1(const ushort* __restrict__ hg,
                            float* __restrict__ Ac, float* __restrict__ Bc) {
  int gid = blockIdx.x * blockDim.x + threadIdx.x;  // B_*NC_*H_/4
  int hq = gid & (H_ / 4 - 1);       // h/4, 0..255
  int c  = (gid >> 8) & (NC_ - 1);
  int b  = gid >> 16;
  const ushort* p = hg + ((size_t)(b * L_ + c * LC_) * (2 * H_)) + hq * 4;
  float As[4] = {0.f, 0.f, 0.f, 0.f};
  float Bv[4] = {-INFINITY, -INFINITY, -INFINITY, -INFINITY};
#pragma unroll 4
  for (int l = 0; l < LC_; ++l) {
    ushort4 hd4 = *reinterpret_cast<const ushort4*>(p);
    ushort4 g4  = *reinterpret_cast<const ushort4*>(p + H_);
    float hdv[4] = {bf2f(hd4.x), bf2f(hd4.y), bf2f(hd4.z), bf2f(hd4.w)};
    float gv[4]  = {bf2f(g4.x),  bf2f(g4.y),  bf2f(g4.z),  bf2f(g4.w)};
#pragma unroll
    for (int j = 0; j < 4; ++j) {
      float lc, v; transform_f(hdv[j], gv[j], lc, v);
      As[j] += lc;
      Bv[j] = logaddexp_f(Bv[j] + lc, v);
    }
    p += 2 * H_;
  }
  size_t o = (size_t)(b * NC_ + c) * H_ + hq * 4;
  *reinterpret_cast<float4*>(&Ac[o]) = make_float4(As[0], As[1], As[2], As[3]);
  *reinterpret_cast<float4*>(&Bc[o]) = make_float4(Bv[0], Bv[1], Bv[2], Bv[3]);
}

// phase 2: per (b, h) exclusive scan over chunk summaries -> carry (incoming log_h per chunk)
__global__ void scan_phase2(const float* __restrict__ Ac, const float* __restrict__ Bc,
                            float* __restrict__ carry) {
  int gid = blockIdx.x * blockDim.x + threadIdx.x;  // B_*H_
  int h = gid & (H_ - 1);
  int b = gid >> 10;
  float P = -INFINITY;
  for (int c = 0; c < NC_; ++c) {
    size_t o = (size_t)(b * NC_ + c) * H_ + h;
    carry[o] = P;
    P = logaddexp_f(P + Ac[o], Bc[o]);
  }
}

// phase 3: re-scan chunk with carry, emit h = exp(log_h) as bf16 (4 channels/thread)
__global__ void scan_phase3(const ushort* __restrict__ hg, const float* __restrict__ carry,
                            ushort* __restrict__ hb) {
  int gid = blockIdx.x * blockDim.x + threadIdx.x;  // B_*NC_*H_/4
  int hq = gid & (H_ / 4 - 1);
  int c  = (gid >> 8) & (NC_ - 1);
  int b  = gid >> 16;
  float4 cr = *reinterpret_cast<const float4*>(&carry[(size_t)(b * NC_ + c) * H_ + hq * 4]);
  float lh[4] = {cr.x, cr.y, cr.z, cr.w};
  const ushort* p = hg + ((size_t)(b * L_ + c * LC_) * (2 * H_)) + hq * 4;
  ushort* q = hb + (size_t)(b * L_ + c * LC_) * H_ + hq * 4;
#pragma unroll 4
  for (int l = 0; l < LC_; ++l) {
    ushort4 hd4 = *reinterpret_cast<const ushort4*>(p);
    ushort4 g4  = *reinterpret_cast<const ushort4*>(p + H_);
    float hdv[4] = {bf2f(hd4.x), bf2f(hd4.y), bf2f(hd4.z), bf2f(hd4.w)};
    float gv[4]  = {bf2f(g4.x),  bf2f(g4.y),  bf2f(g4.z),  bf2f(g4.w)};
    ushort4 o;
    ushort* op = &o.x;
#pragma unroll
    for (int j = 0; j < 4; ++j) {
      float lc, v; transform_f(hdv[j], gv[j], lc, v);
      lh[j] = logaddexp_f(lh[j] + lc, v);
      op[j] = f2bf(__expf(lh[j]));
    }
    *reinterpret_cast<ushort4*>(q) = o;
    p += 2 * H_;
    q += H_;
  }
}

extern "C" void kernel_launch(void* const* d_in, const int* in_sizes, int n_in,
                              void* d_out, int out_size, void* d_ws, size_t ws_size,
                              hipStream_t stream) {
  const float* x     = (const float*)d_in[0];
  const float* W_in  = (const float*)d_in[1];
  const float* b_in  = (const float*)d_in[2];
  const float* W_out = (const float*)d_in[3];
  const float* b_out = (const float*)d_in[4];
  float* out = (float*)d_out;

  char* ws = (char*)d_ws;
  size_t off = 0;
  auto alloc = [&](size_t bytes) {
    void* p = ws + off;
    off = (off + bytes + 255) & ~(size_t)255;
    return p;
  };
  // region shared by xb (alive: cast -> GEMM1) and hb (alive: phase3 -> GEMM2)
  ushort* xb    = (ushort*)alloc((size_t)B_ * L_ * H_ * 2);       // 67 MB (union)
  ushort* hb    = xb;
  ushort* Wib   = (ushort*)alloc((size_t)2 * H_ * D_ * 2);        // 2 MB
  ushort* Wob   = (ushort*)alloc((size_t)D_ * H_ * 2);            // 1 MB
  ushort* hgb   = (ushort*)alloc((size_t)B_ * L_ * 2 * H_ * 2);   // 134 MB (bf16)
  float*  Ac    = (float*)alloc((size_t)B_ * NC_ * H_ * 4);       // 4 MB
  float*  Bc    = (float*)alloc((size_t)B_ * NC_ * H_ * 4);       // 4 MB
  float*  carry = (float*)alloc((size_t)B_ * NC_ * H_ * 4);       // 4 MB
  // total ~216 MB

  // casts to bf16
  cast_kernel<<<(B_ * L_ * D_ / 4 + 255) / 256, 256, 0, stream>>>(x, xb, B_ * L_ * D_ / 4);
  {
    int n0 = 2 * H_ * D_ / 4, n1 = D_ * H_ / 4;
    cast2_kernel<<<(n0 + n1 + 255) / 256, 256, 0, stream>>>(W_in, Wib, n0, W_out, Wob, n1);
  }

  // GEMM1: hg = x . W_in^T + b_in   (M=32768, N=2048, K=512), bf16 out
  gemm_bt<true><<<dim3((2 * H_) / 256, (B_ * L_) / 256), 512, 0, stream>>>(
      xb, Wib, b_in, hgb, B_ * L_, 2 * H_, D_);

  // chunked scan along L (4 channels per thread)
  scan_phase1<<<(B_ * NC_ * H_ / 4) / 256, 256, 0, stream>>>(hgb, Ac, Bc);
  scan_phase2<<<(B_ * H_) / 256, 256, 0, stream>>>(Ac, Bc, carry);
  scan_phase3<<<(B_ * NC_ * H_ / 4) / 256, 256, 0, stream>>>(hgb, carry, hb);

  // GEMM2: out = h . W_out^T + b_out   (M=32768, N=512, K=1024), fp32 out
  gemm_bt<false><<<dim3(D_ / 256, (B_ * L_) / 256), 512, 0, stream>>>(
      hb, Wob, b_out, out, B_ * L_, D_, H_);
}

// Round 2
// 428.317 us; speedup vs baseline: 1.0502x; 1.0175x over previous
//
#include <hip/hip_runtime.h>
#include <hip/hip_bf16.h>
#include <cstdint>
#include <cstddef>

#define B_ 4
#define L_ 8192
#define D_ 512
#define H_ 1024
#define NC_ 256           // chunks along L for the 3-phase scan
#define LC_ (L_ / NC_)    // 32

typedef float  f32x4 __attribute__((ext_vector_type(4)));
typedef short  s16x8 __attribute__((ext_vector_type(8)));
typedef __bf16 b16x8 __attribute__((ext_vector_type(8)));

// ---- MFMA wrapper: tolerate either builtin signature (v8i16 or v8bf16) ----
template <typename T, typename U>
__device__ inline auto mfma_sel(T a, T b, f32x4 c, U, int)
    -> decltype(__builtin_amdgcn_mfma_f32_16x16x32_bf16(a, b, c, 0, 0, 0)) {
  return __builtin_amdgcn_mfma_f32_16x16x32_bf16(a, b, c, 0, 0, 0);
}
template <typename T, typename U>
__device__ inline f32x4 mfma_sel(T a, T b, f32x4 c, U, long) {
  return __builtin_amdgcn_mfma_f32_16x16x32_bf16(
      __builtin_bit_cast(U, a), __builtin_bit_cast(U, b), c, 0, 0, 0);
}
__device__ inline f32x4 mfma_bf16_16x16x32(s16x8 a, s16x8 b, f32x4 c) {
  return mfma_sel(a, b, c, b16x8{}, 0);
}

// ---- fp32 <-> bf16 ----
__device__ inline ushort f2bf(float f) {
  uint32_t u = __builtin_bit_cast(uint32_t, f);
  uint32_t r = (u + 0x7fffu + ((u >> 16) & 1u)) >> 16;
  return (ushort)r;
}
__device__ inline float bf2f(ushort u) {
  return __builtin_bit_cast(float, (uint32_t)u << 16);
}

__global__ void cast_kernel(const float* __restrict__ in, ushort* __restrict__ out, int n4) {
  int i = blockIdx.x * blockDim.x + threadIdx.x;
  if (i >= n4) return;
  float4 f = reinterpret_cast<const float4*>(in)[i];
  ushort4 o;
  o.x = f2bf(f.x); o.y = f2bf(f.y); o.z = f2bf(f.z); o.w = f2bf(f.w);
  reinterpret_cast<ushort4*>(out)[i] = o;
}

// both weights in one launch
__global__ void cast2_kernel(const float* __restrict__ in0, ushort* __restrict__ out0, int n4_0,
                             const float* __restrict__ in1, ushort* __restrict__ out1, int n4_1) {
  int i = blockIdx.x * blockDim.x + threadIdx.x;
  const float* in; ushort* out;
  if (i < n4_0) { in = in0; out = out0; }
  else { i -= n4_0; if (i >= n4_1) return; in = in1; out = out1; }
  float4 f = reinterpret_cast<const float4*>(in)[i];
  ushort4 o;
  o.x = f2bf(f.x); o.y = f2bf(f.y); o.z = f2bf(f.z); o.w = f2bf(f.w);
  reinterpret_cast<ushort4*>(out)[i] = o;
}

#define GLDS(srcp, dstp)                                                            \
  __builtin_amdgcn_global_load_lds(                                                 \
      (const __attribute__((address_space(1))) void*)(srcp),                        \
      (__attribute__((address_space(3))) void*)(dstp), 16, 0, 0)

// barrier with full compiler memory fence (raw s_barrier; vmcnt managed manually)
#define BAR()                               \
  do {                                      \
    asm volatile("" ::: "memory");          \
    __builtin_amdgcn_s_barrier();           \
    asm volatile("" ::: "memory");          \
  } while (0)

// ---- NT GEMM: C[m][n] = sum_k A[m][k]*Bm[n][k] + bias[n]; A:MxK, Bm:NxK (row-major bf16) ----
// 256x256 tile, BK=32, 512 threads = 8 waves (2M x 4N), per-wave 128x64 output (acc[8][4]).
// 4-deep LDS ring (4 x 32 KB = 128 KiB). Tile t+3's loads are issued during tile t's phases
// (2 A-loads in phase 1, 2 B-loads in phase 2), so 3 tiles are always in flight and the
// counted vmcnt at tile top is 8 (tail: 4, then 0) -- never drains mid-loop (T3+T4).
// 2 phases/tile: {ds_read frags; stage-issue; barrier; setprio(1); 16 MFMA; setprio(0);
// barrier}. LDS swizzle for 64B rows: physical 16B chunk p of row r holds logical chunk
// p ^ ((r>>1)&3); staging lane fetches global chunk (lane&3)^((lane>>3)&3) so the linear
// global_load_lds write realizes the swizzle; frag read uses quad ^ ((l15>>1)&3) ->
// 8 rows hit 8 distinct bank-quads (2-way aliasing = free).
// XCD-aware bijective block swizzle (T1; both grids divisible by 8).
template <bool OUT_BF16>
__global__ __launch_bounds__(512, 2)
void gemm_bt(const ushort* __restrict__ A, const ushort* __restrict__ Bm,
             const float* __restrict__ bias, void* __restrict__ Cv,
             int M, int N, int K) {
  __shared__ ushort As[4][256 * 32];
  __shared__ ushort Bs[4][256 * 32];
  const int tid  = threadIdx.x;
  const int wave = tid >> 6;
  const int lane = tid & 63;
  const int l15  = lane & 15;
  const int quad = lane >> 4;

  // XCD swizzle: dispatch index d goes to XCD d%8; give each XCD a contiguous logical chunk.
  int id = blockIdx.y * gridDim.x + blockIdx.x;
  const int nwg = gridDim.x * gridDim.y;
  id = (id & 7) * (nwg >> 3) + (id >> 3);
  const int bxi = id % gridDim.x;
  const int byi = id / gridDim.x;

  const long bm = (long)byi * 256;
  const long bn = (long)bxi * 256;
  const int  wm = (wave >> 2) * 128;   // 0 or 128
  const int  wn = (wave & 3) * 64;     // 0,64,128,192

  f32x4 acc[8][4];
#pragma unroll
  for (int i = 0; i < 8; ++i)
#pragma unroll
    for (int j = 0; j < 4; ++j) acc[i][j] = (f32x4){0.f, 0.f, 0.f, 0.f};

  // staging: one global_load_lds covers 16 rows x 64B. Lane l -> row (l>>2), phys chunk
  // (l&3); global logical chunk = (l&3) ^ ((l>>3)&3)  [= phys ^ ((row>>1)&3)].
  const int rl = lane >> 2;                       // 0..15 row within 16-row group
  const int cb = (lane & 3) ^ ((lane >> 3) & 3);  // swizzled global 16B-chunk
  const ushort* gA = A  + (bm + wave * 16 + rl) * (long)K + cb * 8;
  const ushort* gB = Bm + (bn + wave * 16 + rl) * (long)K + cb * 8;
  const int dst0 = (wave * 16) * 32;          // ushort offset of wave's low 16-row group
  const int dst1 = (wave * 16 + 128) * 32;    // high group

  // fragment-read swizzled chunk offset (ushort units)
  const int sq = (quad ^ ((l15 >> 1) & 3)) * 8;
  int arow[8], brow[4];
#pragma unroll
  for (int i = 0; i < 8; ++i) arow[i] = (wm + i * 16 + l15) * 32;
#pragma unroll
  for (int j = 0; j < 4; ++j) brow[j] = (wn + j * 16 + l15) * 32;

  const int nkt = K >> 5;

  // prologue: stage tiles 0..2 (per tile: A low, A high, B low, B high -> 4 per wave)
  const int npre = nkt < 3 ? nkt : 3;
  for (int pt = 0; pt < npre; ++pt) {
    GLDS(gA + (long)pt * 32,            &As[pt][dst0]);
    GLDS(gA + 128L * K + (long)pt * 32, &As[pt][dst1]);
    GLDS(gB + (long)pt * 32,            &Bs[pt][dst0]);
    GLDS(gB + 128L * K + (long)pt * 32, &Bs[pt][dst1]);
  }

  for (int t = 0; t < nkt; ++t) {
    // tile-t readiness: wait for own loads (groups are tile-ordered), then barrier for
    // all-waves visibility. ahead = tiles already issued beyond t (4 loads each).
    const int ahead = nkt - 1 - t;
    if (ahead >= 2)      asm volatile("s_waitcnt vmcnt(8)" ::: "memory");
    else if (ahead == 1) asm volatile("s_waitcnt vmcnt(4)" ::: "memory");
    else                 asm volatile("s_waitcnt vmcnt(0)" ::: "memory");
    BAR();

    const ushort* Ac = As[t & 3];
    const ushort* Bc = Bs[t & 3];
    const int tp = t + 3;
    const bool pf = tp < nkt;

    // ---- phase 1: m-half 0 ----
    s16x8 bf[4], af[4];
#pragma unroll
    for (int j = 0; j < 4; ++j)
      bf[j] = *reinterpret_cast<const s16x8*>(&Bc[brow[j] + sq]);
#pragma unroll
    for (int i = 0; i < 4; ++i)
      af[i] = *reinterpret_cast<const s16x8*>(&Ac[arow[i] + sq]);
    if (pf) {
      // WAR safe: buf[(t+3)&3] == buf[(t-1)&3]; its reads finished before iter t-1's
      // final barrier, and we are past it.
      GLDS(gA + (long)tp * 32,            &As[tp & 3][dst0]);
      GLDS(gA + 128L * K + (long)tp * 32, &As[tp & 3][dst1]);
    }
    BAR();
    __builtin_amdgcn_s_setprio(1);
#pragma unroll
    for (int i = 0; i < 4; ++i)
#pragma unroll
      for (int j = 0; j < 4; ++j)
        acc[i][j] = mfma_bf16_16x16x32(af[i], bf[j], acc[i][j]);
    __builtin_amdgcn_s_setprio(0);
    BAR();

    // ---- phase 2: m-half 1 (reuse bf) ----
#pragma unroll
    for (int i = 0; i < 4; ++i)
      af[i] = *reinterpret_cast<const s16x8*>(&Ac[arow[4 + i] + sq]);
    if (pf) {
      GLDS(gB + (long)tp * 32,            &Bs[tp & 3][dst0]);
      GLDS(gB + 128L * K + (long)tp * 32, &Bs[tp & 3][dst1]);
    }
    BAR();
    __builtin_amdgcn_s_setprio(1);
#pragma unroll
    for (int i = 0; i < 4; ++i)
#pragma unroll
      for (int j = 0; j < 4; ++j)
        acc[4 + i][j] = mfma_bf16_16x16x32(af[i], bf[j], acc[4 + i][j]);
    __builtin_amdgcn_s_setprio(0);
    BAR();
  }

  // epilogue: C/D layout col = lane&15, row = quad*4 + reg
#pragma unroll
  for (int mi = 0; mi < 8; ++mi) {
    const long mrow = bm + wm + mi * 16 + quad * 4;
#pragma unroll
    for (int ni = 0; ni < 4; ++ni) {
      const long ncol = bn + wn + ni * 16 + l15;
      const float bv = bias[ncol];
      if (OUT_BF16) {
        ushort* cp = (ushort*)Cv + mrow * (long)N + ncol;
#pragma unroll
        for (int r = 0; r < 4; ++r) cp[(long)r * N] = f2bf(acc[mi][ni][r] + bv);
      } else {
        float* cp = (float*)Cv + mrow * (long)N + ncol;
#pragma unroll
        for (int r = 0; r < 4; ++r) cp[(long)r * N] = acc[mi][ni][r] + bv;
      }
    }
  }
}

// ---- scan helpers ----
__device__ inline float softplus_f(float x) {
  return fmaxf(x, 0.f) + __logf(1.f + __expf(-fabsf(x)));
}
__device__ inline float logaddexp_f(float a, float b) {
  float m = fmaxf(a, b);
  return m + __logf(1.f + __expf(-fabsf(a - b)));
}
// from (hidden, gate): lc = -softplus(g); v = log_z + log_tilde_h
__device__ inline void transform_f(float hd, float g, float& lc, float& v) {
  float sp = softplus_f(g);
  lc = -sp;
  float lz = g - sp;                       // -softplus(-g)
  float lth = (hd >= 0.f) ? __logf(hd + 0.5f) : (hd - softplus_f(hd));
  v = lz + lth;
}

// phase 1: per (b, chunk, h-quad) compute chunk composition (Asum, Bv) for 4 channels
__global__ void scan_phase1(const ushort* __restrict__ hg,
                            float* __restrict__ Ac, float* __restrict__ Bc) {
  int gid = blockIdx.x * blockDim.x + threadIdx.x;  // B_*NC_*H_/4
  int hq = gid & (H_ / 4 - 1);       // h/4, 0..255
  int c  = (gid >> 8) & (NC_ - 1);
  int b  = gid >> 16;
  const ushort* p = hg + ((size_t)(b * L_ + c * LC_) * (2 * H_)) + hq * 4;
  float As[4] = {0.f, 0.f, 0.f, 0.f};
  float Bv[4] = {-INFINITY, -INFINITY, -INFINITY, -INFINITY};
#pragma unroll 4
  for (int l = 0; l < LC_; ++l) {
    ushort4 hd4 = *reinterpret_cast<const ushort4*>(p);
    ushort4 g4  = *reinterpret_cast<const ushort4*>(p + H_);
    float hdv[4] = {bf2f(hd4.x), bf2f(hd4.y), bf2f(hd4.z), bf2f(hd4.w)};
    float gv[4]  = {bf2f(g4.x),  bf2f(g4.y),  bf2f(g4.z),  bf2f(g4.w)};
#pragma unroll
    for (int j = 0; j < 4; ++j) {
      float lc, v; transform_f(hdv[j], gv[j], lc, v);
      As[j] += lc;
      Bv[j] = logaddexp_f(Bv[j] + lc, v);
    }
    p += 2 * H_;
  }
  size_t o = (size_t)(b * NC_ + c) * H_ + hq * 4;
  *reinterpret_cast<float4*>(&Ac[o]) = make_float4(As[0], As[1], As[2], As[3]);
  *reinterpret_cast<float4*>(&Bc[o]) = make_float4(Bv[0], Bv[1], Bv[2], Bv[3]);
}

// phase 2: per (b, h) exclusive scan over chunk summaries -> carry (incoming log_h per chunk)
__global__ void scan_phase2(const float* __restrict__ Ac, const float* __restrict__ Bc,
                            float* __restrict__ carry) {
  int gid = blockIdx.x * blockDim.x + threadIdx.x;  // B_*H_
  int h = gid & (H_ - 1);
  int b = gid >> 10;
  float P = -INFINITY;
  for (int c = 0; c < NC_; ++c) {
    size_t o = (size_t)(b * NC_ + c) * H_ + h;
    carry[o] = P;
    P = logaddexp_f(P + Ac[o], Bc[o]);
  }
}

// phase 3: re-scan chunk with carry, emit h = exp(log_h) as bf16 (4 channels/thread)
__global__ void scan_phase3(const ushort* __restrict__ hg, const float* __restrict__ carry,
                            ushort* __restrict__ hb) {
  int gid = blockIdx.x * blockDim.x + threadIdx.x;  // B_*NC_*H_/4
  int hq = gid & (H_ / 4 - 1);
  int c  = (gid >> 8) & (NC_ - 1);
  int b  = gid >> 16;
  float4 cr = *reinterpret_cast<const float4*>(&carry[(size_t)(b * NC_ + c) * H_ + hq * 4]);
  float lh[4] = {cr.x, cr.y, cr.z, cr.w};
  const ushort* p = hg + ((size_t)(b * L_ + c * LC_) * (2 * H_)) + hq * 4;
  ushort* q = hb + (size_t)(b * L_ + c * LC_) * H_ + hq * 4;
#pragma unroll 4
  for (int l = 0; l < LC_; ++l) {
    ushort4 hd4 = *reinterpret_cast<const ushort4*>(p);
    ushort4 g4  = *reinterpret_cast<const ushort4*>(p + H_);
    float hdv[4] = {bf2f(hd4.x), bf2f(hd4.y), bf2f(hd4.z), bf2f(hd4.w)};
    float gv[4]  = {bf2f(g4.x),  bf2f(g4.y),  bf2f(g4.z),  bf2f(g4.w)};
    ushort4 o;
    ushort* op = &o.x;
#pragma unroll
    for (int j = 0; j < 4; ++j) {
      float lc, v; transform_f(hdv[j], gv[j], lc, v);
      lh[j] = logaddexp_f(lh[j] + lc, v);
      op[j] = f2bf(__expf(lh[j]));
    }
    *reinterpret_cast<ushort4*>(q) = o;
    p += 2 * H_;
    q += H_;
  }
}

extern "C" void kernel_launch(void* const* d_in, const int* in_sizes, int n_in,
                              void* d_out, int out_size, void* d_ws, size_t ws_size,
                              hipStream_t stream) {
  const float* x     = (const float*)d_in[0];
  const float* W_in  = (const float*)d_in[1];
  const float* b_in  = (const float*)d_in[2];
  const float* W_out = (const float*)d_in[3];
  const float* b_out = (const float*)d_in[4];
  float* out = (float*)d_out;

  char* ws = (char*)d_ws;
  size_t off = 0;
  auto alloc = [&](size_t bytes) {
    void* p = ws + off;
    off = (off + bytes + 255) & ~(size_t)255;
    return p;
  };
  // region shared by xb (alive: cast -> GEMM1) and hb (alive: phase3 -> GEMM2)
  ushort* xb    = (ushort*)alloc((size_t)B_ * L_ * H_ * 2);       // 67 MB (union)
  ushort* hb    = xb;
  ushort* Wib   = (ushort*)alloc((size_t)2 * H_ * D_ * 2);        // 2 MB
  ushort* Wob   = (ushort*)alloc((size_t)D_ * H_ * 2);            // 1 MB
  ushort* hgb   = (ushort*)alloc((size_t)B_ * L_ * 2 * H_ * 2);   // 134 MB (bf16)
  float*  Ac    = (float*)alloc((size_t)B_ * NC_ * H_ * 4);       // 4 MB
  float*  Bc    = (float*)alloc((size_t)B_ * NC_ * H_ * 4);       // 4 MB
  float*  carry = (float*)alloc((size_t)B_ * NC_ * H_ * 4);       // 4 MB
  // total ~216 MB

  // casts to bf16
  cast_kernel<<<(B_ * L_ * D_ / 4 + 255) / 256, 256, 0, stream>>>(x, xb, B_ * L_ * D_ / 4);
  {
    int n0 = 2 * H_ * D_ / 4, n1 = D_ * H_ / 4;
    cast2_kernel<<<(n0 + n1 + 255) / 256, 256, 0, stream>>>(W_in, Wib, n0, W_out, Wob, n1);
  }

  // GEMM1: hg = x . W_in^T + b_in   (M=32768, N=2048, K=512), bf16 out
  gemm_bt<true><<<dim3((2 * H_) / 256, (B_ * L_) / 256), 512, 0, stream>>>(
      xb, Wib, b_in, hgb, B_ * L_, 2 * H_, D_);

  // chunked scan along L (4 channels per thread)
  scan_phase1<<<(B_ * NC_ * H_ / 4) / 256, 256, 0, stream>>>(hgb, Ac, Bc);
  scan_phase2<<<(B_ * H_) / 256, 256, 0, stream>>>(Ac, Bc, carry);
  scan_phase3<<<(B_ * NC_ * H_ / 4) / 256, 256, 0, stream>>>(hgb, carry, hb);

  // GEMM2: out = h . W_out^T + b_out   (M=32768, N=512, K=1024), fp32 out
  gemm_bt<false><<<dim3(D_ / 256, (B_ * L_) / 256), 512, 0, stream>>>(
      hb, Wob, b_out, out, B_ * L_, D_, H_);
}

// Round 3
// 423.665 us; speedup vs baseline: 1.0617x; 1.0110x over previous
//
#include <hip/hip_runtime.h>
#include <hip/hip_bf16.h>
#include <cstdint>
#include <cstddef>

#define B_ 4
#define L_ 8192
#define D_ 512
#define H_ 1024
#define NC_ 256           // chunks along L for the 3-phase scan
#define LC_ (L_ / NC_)    // 32

typedef float  f32x4 __attribute__((ext_vector_type(4)));
typedef short  s16x8 __attribute__((ext_vector_type(8)));
typedef __bf16 b16x8 __attribute__((ext_vector_type(8)));

// ---- MFMA wrapper: tolerate either builtin signature (v8i16 or v8bf16) ----
template <typename T, typename U>
__device__ inline auto mfma_sel(T a, T b, f32x4 c, U, int)
    -> decltype(__builtin_amdgcn_mfma_f32_16x16x32_bf16(a, b, c, 0, 0, 0)) {
  return __builtin_amdgcn_mfma_f32_16x16x32_bf16(a, b, c, 0, 0, 0);
}
template <typename T, typename U>
__device__ inline f32x4 mfma_sel(T a, T b, f32x4 c, U, long) {
  return __builtin_amdgcn_mfma_f32_16x16x32_bf16(
      __builtin_bit_cast(U, a), __builtin_bit_cast(U, b), c, 0, 0, 0);
}
__device__ inline f32x4 mfma_bf16_16x16x32(s16x8 a, s16x8 b, f32x4 c) {
  return mfma_sel(a, b, c, b16x8{}, 0);
}

// ---- fp32 <-> bf16 ----
__device__ inline ushort f2bf(float f) {
  uint32_t u = __builtin_bit_cast(uint32_t, f);
  uint32_t r = (u + 0x7fffu + ((u >> 16) & 1u)) >> 16;
  return (ushort)r;
}
__device__ inline float bf2f(ushort u) {
  return __builtin_bit_cast(float, (uint32_t)u << 16);
}

__global__ void cast_kernel(const float* __restrict__ in, ushort* __restrict__ out, int n4) {
  int i = blockIdx.x * blockDim.x + threadIdx.x;
  if (i >= n4) return;
  float4 f = reinterpret_cast<const float4*>(in)[i];
  ushort4 o;
  o.x = f2bf(f.x); o.y = f2bf(f.y); o.z = f2bf(f.z); o.w = f2bf(f.w);
  reinterpret_cast<ushort4*>(out)[i] = o;
}

// both weights in one launch
__global__ void cast2_kernel(const float* __restrict__ in0, ushort* __restrict__ out0, int n4_0,
                             const float* __restrict__ in1, ushort* __restrict__ out1, int n4_1) {
  int i = blockIdx.x * blockDim.x + threadIdx.x;
  const float* in; ushort* out;
  if (i < n4_0) { in = in0; out = out0; }
  else { i -= n4_0; if (i >= n4_1) return; in = in1; out = out1; }
  float4 f = reinterpret_cast<const float4*>(in)[i];
  ushort4 o;
  o.x = f2bf(f.x); o.y = f2bf(f.y); o.z = f2bf(f.z); o.w = f2bf(f.w);
  reinterpret_cast<ushort4*>(out)[i] = o;
}

#define GLDS(srcp, dstp)                                                            \
  __builtin_amdgcn_global_load_lds(                                                 \
      (const __attribute__((address_space(1))) void*)(srcp),                        \
      (__attribute__((address_space(3))) void*)(dstp), 16, 0, 0)

// barrier with full compiler memory fence (raw s_barrier; vmcnt managed manually)
#define BAR()                               \
  do {                                      \
    asm volatile("" ::: "memory");          \
    __builtin_amdgcn_s_barrier();           \
    asm volatile("" ::: "memory");          \
  } while (0)

// ---- NT GEMM: C[m][n] = sum_k A[m][k]*Bm[n][k] + bias[n]; A:MxK, Bm:NxK (row-major bf16) ----
// 256x256 tile, BK=64, 512 threads = 8 waves (2M x 4N), per-wave 128x64 output (acc[8][4]).
// Double-buffered LDS (2 x 64 KB). m201-style 4-balanced-phase schedule per K-step:
//   ph1: {read 4 B-frags(kh0) + 4 A-lo(kh0); stage A(t+1) 4x gload; bar; 16 MFMA (mh0,kh0); bar}
//   ph2: {read 4 A-hi(kh0);                  stage B(t+1) 4x gload; bar; 16 MFMA (mh1,kh0); bar}
//   ph3: {read 4 B-frags(kh1) + 4 A-lo(kh1);                       bar; 16 MFMA (mh0,kh1); bar}
//   ph4: {read 4 A-hi(kh1);                                        bar; 16 MFMA (mh1,kh1);
//         vmcnt(0) after MFMA-issue (t+1's loads had ~2-3 phases to land -> near-free); bar}
// 8 barriers + 1 cheap vmcnt per K-64 (vs 10+2 at BK=32), balanced 8/4/8/4 read bursts.
// LDS swizzle (128B rows, 8x16B chunks): phys chunk p of row r holds logical chunk p^(r&7);
// staging lane (rl=lane>>3, slot=lane&7) fetches global chunk slot^rl; frag read uses
// (kh*4+quad)^(l15&7). Measured 0 bank conflicts (R0/R1).
// XCD-aware block swizzle (both grids divisible by 8). setprio(1) around MFMA clusters.
template <bool OUT_BF16>
__global__ __launch_bounds__(512, 2)
void gemm_bt(const ushort* __restrict__ A, const ushort* __restrict__ Bm,
             const float* __restrict__ bias, void* __restrict__ Cv,
             int M, int N, int K) {
  __shared__ ushort As[2][256 * 64];
  __shared__ ushort Bs[2][256 * 64];
  const int tid  = threadIdx.x;
  const int wave = tid >> 6;
  const int lane = tid & 63;
  const int l15  = lane & 15;
  const int quad = lane >> 4;

  // XCD swizzle: dispatch index d goes to XCD d%8; give each XCD a contiguous logical chunk.
  int id = blockIdx.y * gridDim.x + blockIdx.x;
  const int nwg = gridDim.x * gridDim.y;
  id = (id & 7) * (nwg >> 3) + (id >> 3);
  const int bxi = id % gridDim.x;
  const int byi = id / gridDim.x;

  const long bm = (long)byi * 256;
  const long bn = (long)bxi * 256;
  const int  wm = (wave >> 2) * 128;   // 0 or 128
  const int  wn = (wave & 3) * 64;     // 0,64,128,192

  f32x4 acc[8][4];
#pragma unroll
  for (int i = 0; i < 8; ++i)
#pragma unroll
    for (int j = 0; j < 4; ++j) acc[i][j] = (f32x4){0.f, 0.f, 0.f, 0.f};

  // staging: wave fills rows [wave*32, wave*32+32); each instr covers 8 rows (64 lanes x 16B).
  // Lane: rl = lane>>3 (row in 8-row group), phys slot = lane&7, global chunk = slot^rl.
  const int rl  = lane >> 3;
  const int cb  = (lane & 7) ^ rl;
  const int srow = wave * 32 + rl;
  const ushort* gA0 = A  + (bm + srow) * (long)K + cb * 8;
  const ushort* gB0 = Bm + (bn + srow) * (long)K + cb * 8;
  int ldst[4];
#pragma unroll
  for (int i = 0; i < 4; ++i) ldst[i] = (wave * 32 + 8 * i) * 64;

  // fragment-read swizzled slot offsets (ushort units): (kh*4+quad) ^ (l15&7)
  const int sq0 = ((0 * 4 + quad) ^ (l15 & 7)) * 8;
  const int sq1 = ((1 * 4 + quad) ^ (l15 & 7)) * 8;
  int arow[8], brow[4];
#pragma unroll
  for (int i = 0; i < 8; ++i) arow[i] = (wm + i * 16 + l15) * 64;
#pragma unroll
  for (int j = 0; j < 4; ++j) brow[j] = (wn + j * 16 + l15) * 64;

  const int nkt = K >> 6;

  // prologue: stage K-step 0 -> buf 0; cold drain (unavoidable once per block)
#pragma unroll
  for (int i = 0; i < 4; ++i) GLDS(gA0 + 8L * i * K, &As[0][ldst[i]]);
#pragma unroll
  for (int i = 0; i < 4; ++i) GLDS(gB0 + 8L * i * K, &Bs[0][ldst[i]]);
  asm volatile("s_waitcnt vmcnt(0)" ::: "memory");
  BAR();

  for (int t = 0; t < nkt; ++t) {
    const int buf  = t & 1;
    const int nbuf = buf ^ 1;
    const bool pf  = (t + 1) < nkt;
    const ushort* Ac = As[buf];
    const ushort* Bc = Bs[buf];
    const long koff = (long)(t + 1) * 64;
    s16x8 bf[4], af[4];

    // ---- phase 1: (mh0, kh0); stage A(t+1) ----
#pragma unroll
    for (int j = 0; j < 4; ++j)
      bf[j] = *reinterpret_cast<const s16x8*>(&Bc[brow[j] + sq0]);
#pragma unroll
    for (int i = 0; i < 4; ++i)
      af[i] = *reinterpret_cast<const s16x8*>(&Ac[arow[i] + sq0]);
    if (pf) {
      // WAR safe: buf nbuf holds K-step t-1, fully consumed before iter t-1's final barrier.
#pragma unroll
      for (int i = 0; i < 4; ++i) GLDS(gA0 + 8L * i * K + koff, &As[nbuf][ldst[i]]);
    }
    BAR();
    __builtin_amdgcn_s_setprio(1);
#pragma unroll
    for (int i = 0; i < 4; ++i)
#pragma unroll
      for (int j = 0; j < 4; ++j)
        acc[i][j] = mfma_bf16_16x16x32(af[i], bf[j], acc[i][j]);
    __builtin_amdgcn_s_setprio(0);
    BAR();

    // ---- phase 2: (mh1, kh0); stage B(t+1) ----
#pragma unroll
    for (int i = 0; i < 4; ++i)
      af[i] = *reinterpret_cast<const s16x8*>(&Ac[arow[4 + i] + sq0]);
    if (pf) {
#pragma unroll
      for (int i = 0; i < 4; ++i) GLDS(gB0 + 8L * i * K + koff, &Bs[nbuf][ldst[i]]);
    }
    BAR();
    __builtin_amdgcn_s_setprio(1);
#pragma unroll
    for (int i = 0; i < 4; ++i)
#pragma unroll
      for (int j = 0; j < 4; ++j)
        acc[4 + i][j] = mfma_bf16_16x16x32(af[i], bf[j], acc[4 + i][j]);
    __builtin_amdgcn_s_setprio(0);
    BAR();

    // ---- phase 3: (mh0, kh1) ----
#pragma unroll
    for (int j = 0; j < 4; ++j)
      bf[j] = *reinterpret_cast<const s16x8*>(&Bc[brow[j] + sq1]);
#pragma unroll
    for (int i = 0; i < 4; ++i)
      af[i] = *reinterpret_cast<const s16x8*>(&Ac[arow[i] + sq1]);
    BAR();
    __builtin_amdgcn_s_setprio(1);
#pragma unroll
    for (int i = 0; i < 4; ++i)
#pragma unroll
      for (int j = 0; j < 4; ++j)
        acc[i][j] = mfma_bf16_16x16x32(af[i], bf[j], acc[i][j]);
    __builtin_amdgcn_s_setprio(0);
    BAR();

    // ---- phase 4: (mh1, kh1); drain t+1's loads after MFMA-issue ----
#pragma unroll
    for (int i = 0; i < 4; ++i)
      af[i] = *reinterpret_cast<const s16x8*>(&Ac[arow[4 + i] + sq1]);
    BAR();
    __builtin_amdgcn_s_setprio(1);
#pragma unroll
    for (int i = 0; i < 4; ++i)
#pragma unroll
      for (int j = 0; j < 4; ++j)
        acc[4 + i][j] = mfma_bf16_16x16x32(af[i], bf[j], acc[4 + i][j]);
    __builtin_amdgcn_s_setprio(0);
    if (pf) asm volatile("s_waitcnt vmcnt(0)" ::: "memory");
    BAR();   // after this barrier, all waves' t+1 loads are visible in LDS
  }

  // epilogue: C/D layout col = lane&15, row = quad*4 + reg
#pragma unroll
  for (int mi = 0; mi < 8; ++mi) {
    const long mrow = bm + wm + mi * 16 + quad * 4;
#pragma unroll
    for (int ni = 0; ni < 4; ++ni) {
      const long ncol = bn + wn + ni * 16 + l15;
      const float bv = bias[ncol];
      if (OUT_BF16) {
        ushort* cp = (ushort*)Cv + mrow * (long)N + ncol;
#pragma unroll
        for (int r = 0; r < 4; ++r) cp[(long)r * N] = f2bf(acc[mi][ni][r] + bv);
      } else {
        float* cp = (float*)Cv + mrow * (long)N + ncol;
#pragma unroll
        for (int r = 0; r < 4; ++r) cp[(long)r * N] = acc[mi][ni][r] + bv;
      }
    }
  }
}

// ---- scan helpers ----
__device__ inline float softplus_f(float x) {
  return fmaxf(x, 0.f) + __logf(1.f + __expf(-fabsf(x)));
}
__device__ inline float logaddexp_f(float a, float b) {
  float m = fmaxf(a, b);
  return m + __logf(1.f + __expf(-fabsf(a - b)));
}
// from (hidden, gate): lc = -softplus(g); v = log_z + log_tilde_h
__device__ inline void transform_f(float hd, float g, float& lc, float& v) {
  float sp = softplus_f(g);
  lc = -sp;
  float lz = g - sp;                       // -softplus(-g)
  float lth = (hd >= 0.f) ? __logf(hd + 0.5f) : (hd - softplus_f(hd));
  v = lz + lth;
}

// phase 1: per (b, chunk, h-quad) compute chunk composition (Asum, Bv) for 4 channels
__global__ void scan_phase1(const ushort* __restrict__ hg,
                            float* __restrict__ Ac, float* __restrict__ Bc) {
  int gid = blockIdx.x * blockDim.x + threadIdx.x;  // B_*NC_*H_/4
  int hq = gid & (H_ / 4 - 1);       // h/4, 0..255
  int c  = (gid >> 8) & (NC_ - 1);
  int b  = gid >> 16;
  const ushort* p = hg + ((size_t)(b * L_ + c * LC_) * (2 * H_)) + hq * 4;
  float As[4] = {0.f, 0.f, 0.f, 0.f};
  float Bv[4] = {-INFINITY, -INFINITY, -INFINITY, -INFINITY};
#pragma unroll 4
  for (int l = 0; l < LC_; ++l) {
    ushort4 hd4 = *reinterpret_cast<const ushort4*>(p);
    ushort4 g4  = *reinterpret_cast<const ushort4*>(p + H_);
    float hdv[4] = {bf2f(hd4.x), bf2f(hd4.y), bf2f(hd4.z), bf2f(hd4.w)};
    float gv[4]  = {bf2f(g4.x),  bf2f(g4.y),  bf2f(g4.z),  bf2f(g4.w)};
#pragma unroll
    for (int j = 0; j < 4; ++j) {
      float lc, v; transform_f(hdv[j], gv[j], lc, v);
      As[j] += lc;
      Bv[j] = logaddexp_f(Bv[j] + lc, v);
    }
    p += 2 * H_;
  }
  size_t o = (size_t)(b * NC_ + c) * H_ + hq * 4;
  *reinterpret_cast<float4*>(&Ac[o]) = make_float4(As[0], As[1], As[2], As[3]);
  *reinterpret_cast<float4*>(&Bc[o]) = make_float4(Bv[0], Bv[1], Bv[2], Bv[3]);
}

// phase 2: per (b, h) exclusive scan over chunk summaries -> carry (incoming log_h per chunk)
__global__ void scan_phase2(const float* __restrict__ Ac, const float* __restrict__ Bc,
                            float* __restrict__ carry) {
  int gid = blockIdx.x * blockDim.x + threadIdx.x;  // B_*H_
  int h = gid & (H_ - 1);
  int b = gid >> 10;
  float P = -INFINITY;
  for (int c = 0; c < NC_; ++c) {
    size_t o = (size_t)(b * NC_ + c) * H_ + h;
    carry[o] = P;
    P = logaddexp_f(P + Ac[o], Bc[o]);
  }
}

// phase 3: re-scan chunk with carry, emit h = exp(log_h) as bf16 (4 channels/thread)
__global__ void scan_phase3(const ushort* __restrict__ hg, const float* __restrict__ carry,
                            ushort* __restrict__ hb) {
  int gid = blockIdx.x * blockDim.x + threadIdx.x;  // B_*NC_*H_/4
  int hq = gid & (H_ / 4 - 1);
  int c  = (gid >> 8) & (NC_ - 1);
  int b  = gid >> 16;
  float4 cr = *reinterpret_cast<const float4*>(&carry[(size_t)(b * NC_ + c) * H_ + hq * 4]);
  float lh[4] = {cr.x, cr.y, cr.z, cr.w};
  const ushort* p = hg + ((size_t)(b * L_ + c * LC_) * (2 * H_)) + hq * 4;
  ushort* q = hb + (size_t)(b * L_ + c * LC_) * H_ + hq * 4;
#pragma unroll 4
  for (int l = 0; l < LC_; ++l) {
    ushort4 hd4 = *reinterpret_cast<const ushort4*>(p);
    ushort4 g4  = *reinterpret_cast<const ushort4*>(p + H_);
    float hdv[4] = {bf2f(hd4.x), bf2f(hd4.y), bf2f(hd4.z), bf2f(hd4.w)};
    float gv[4]  = {bf2f(g4.x),  bf2f(g4.y),  bf2f(g4.z),  bf2f(g4.w)};
    ushort4 o;
    ushort* op = &o.x;
#pragma unroll
    for (int j = 0; j < 4; ++j) {
      float lc, v; transform_f(hdv[j], gv[j], lc, v);
      lh[j] = logaddexp_f(lh[j] + lc, v);
      op[j] = f2bf(__expf(lh[j]));
    }
    *reinterpret_cast<ushort4*>(q) = o;
    p += 2 * H_;
    q += H_;
  }
}

extern "C" void kernel_launch(void* const* d_in, const int* in_sizes, int n_in,
                              void* d_out, int out_size, void* d_ws, size_t ws_size,
                              hipStream_t stream) {
  const float* x     = (const float*)d_in[0];
  const float* W_in  = (const float*)d_in[1];
  const float* b_in  = (const float*)d_in[2];
  const float* W_out = (const float*)d_in[3];
  const float* b_out = (const float*)d_in[4];
  float* out = (float*)d_out;

  char* ws = (char*)d_ws;
  size_t off = 0;
  auto alloc = [&](size_t bytes) {
    void* p = ws + off;
    off = (off + bytes + 255) & ~(size_t)255;
    return p;
  };
  // region shared by xb (alive: cast -> GEMM1) and hb (alive: phase3 -> GEMM2)
  ushort* xb    = (ushort*)alloc((size_t)B_ * L_ * H_ * 2);       // 67 MB (union)
  ushort* hb    = xb;
  ushort* Wib   = (ushort*)alloc((size_t)2 * H_ * D_ * 2);        // 2 MB
  ushort* Wob   = (ushort*)alloc((size_t)D_ * H_ * 2);            // 1 MB
  ushort* hgb   = (ushort*)alloc((size_t)B_ * L_ * 2 * H_ * 2);   // 134 MB (bf16)
  float*  Ac    = (float*)alloc((size_t)B_ * NC_ * H_ * 4);       // 4 MB
  float*  Bc    = (float*)alloc((size_t)B_ * NC_ * H_ * 4);       // 4 MB
  float*  carry = (float*)alloc((size_t)B_ * NC_ * H_ * 4);       // 4 MB
  // total ~216 MB

  // casts to bf16
  cast_kernel<<<(B_ * L_ * D_ / 4 + 255) / 256, 256, 0, stream>>>(x, xb, B_ * L_ * D_ / 4);
  {
    int n0 = 2 * H_ * D_ / 4, n1 = D_ * H_ / 4;
    cast2_kernel<<<(n0 + n1 + 255) / 256, 256, 0, stream>>>(W_in, Wib, n0, W_out, Wob, n1);
  }

  // GEMM1: hg = x . W_in^T + b_in   (M=32768, N=2048, K=512), bf16 out
  gemm_bt<true><<<dim3((2 * H_) / 256, (B_ * L_) / 256), 512, 0, stream>>>(
      xb, Wib, b_in, hgb, B_ * L_, 2 * H_, D_);

  // chunked scan along L (4 channels per thread)
  scan_phase1<<<(B_ * NC_ * H_ / 4) / 256, 256, 0, stream>>>(hgb, Ac, Bc);
  scan_phase2<<<(B_ * H_) / 256, 256, 0, stream>>>(Ac, Bc, carry);
  scan_phase3<<<(B_ * NC_ * H_ / 4) / 256, 256, 0, stream>>>(hgb, carry, hb);

  // GEMM2: out = h . W_out^T + b_out   (M=32768, N=512, K=1024), fp32 out
  gemm_bt<false><<<dim3(D_ / 256, (B_ * L_) / 256), 512, 0, stream>>>(
      hb, Wob, b_out, out, B_ * L_, D_, H_);
}

// Round 4
// 386.396 us; speedup vs baseline: 1.1641x; 1.0965x over previous
//
#include <hip/hip_runtime.h>
#include <hip/hip_bf16.h>
#include <cstdint>
#include <cstddef>

#define B_ 4
#define L_ 8192
#define D_ 512
#define H_ 1024
#define NC_ 256           // chunks along L for the 3-phase scan
#define LC_ (L_ / NC_)    // 32

typedef float  f32x4 __attribute__((ext_vector_type(4)));
typedef short  s16x8 __attribute__((ext_vector_type(8)));
typedef __bf16 b16x8 __attribute__((ext_vector_type(8)));

// ---- MFMA wrapper: tolerate either builtin signature (v8i16 or v8bf16) ----
template <typename T, typename U>
__device__ inline auto mfma_sel(T a, T b, f32x4 c, U, int)
    -> decltype(__builtin_amdgcn_mfma_f32_16x16x32_bf16(a, b, c, 0, 0, 0)) {
  return __builtin_amdgcn_mfma_f32_16x16x32_bf16(a, b, c, 0, 0, 0);
}
template <typename T, typename U>
__device__ inline f32x4 mfma_sel(T a, T b, f32x4 c, U, long) {
  return __builtin_amdgcn_mfma_f32_16x16x32_bf16(
      __builtin_bit_cast(U, a), __builtin_bit_cast(U, b), c, 0, 0, 0);
}
__device__ inline f32x4 mfma_bf16_16x16x32(s16x8 a, s16x8 b, f32x4 c) {
  return mfma_sel(a, b, c, b16x8{}, 0);
}

// ---- fp32 <-> bf16 ----
__device__ inline ushort f2bf(float f) {
  uint32_t u = __builtin_bit_cast(uint32_t, f);
  uint32_t r = (u + 0x7fffu + ((u >> 16) & 1u)) >> 16;
  return (ushort)r;
}
__device__ inline float bf2f(ushort u) {
  return __builtin_bit_cast(float, (uint32_t)u << 16);
}

// ---- scan math helpers ----
__device__ inline float softplus_f(float x) {
  return fmaxf(x, 0.f) + __logf(1.f + __expf(-fabsf(x)));
}
__device__ inline float logaddexp_f(float a, float b) {
  float m = fmaxf(a, b);
  return m + __logf(1.f + __expf(-fabsf(a - b)));
}
// from (hidden, gate): lc = -softplus(g); v = log_z + log_tilde_h
__device__ inline void transform_f(float hd, float g, float& lc, float& v) {
  float sp = softplus_f(g);
  lc = -sp;
  float lz = g - sp;                       // -softplus(-g)
  float lth = (hd >= 0.f) ? __logf(hd + 0.5f) : (hd - softplus_f(hd));
  v = lz + lth;
}

__global__ void cast_kernel(const float* __restrict__ in, ushort* __restrict__ out, int n4) {
  int i = blockIdx.x * blockDim.x + threadIdx.x;
  if (i >= n4) return;
  float4 f = reinterpret_cast<const float4*>(in)[i];
  ushort4 o;
  o.x = f2bf(f.x); o.y = f2bf(f.y); o.z = f2bf(f.z); o.w = f2bf(f.w);
  reinterpret_cast<ushort4*>(out)[i] = o;
}

// both weights in one launch
__global__ void cast2_kernel(const float* __restrict__ in0, ushort* __restrict__ out0, int n4_0,
                             const float* __restrict__ in1, ushort* __restrict__ out1, int n4_1) {
  int i = blockIdx.x * blockDim.x + threadIdx.x;
  const float* in; ushort* out;
  if (i < n4_0) { in = in0; out = out0; }
  else { i -= n4_0; if (i >= n4_1) return; in = in1; out = out1; }
  float4 f = reinterpret_cast<const float4*>(in)[i];
  ushort4 o;
  o.x = f2bf(f.x); o.y = f2bf(f.y); o.z = f2bf(f.z); o.w = f2bf(f.w);
  reinterpret_cast<ushort4*>(out)[i] = o;
}

#define GLDS(srcp, dstp)                                                            \
  __builtin_amdgcn_global_load_lds(                                                 \
      (const __attribute__((address_space(1))) void*)(srcp),                        \
      (__attribute__((address_space(3))) void*)(dstp), 16, 0, 0)

// barrier with full compiler memory fence (raw s_barrier; vmcnt managed manually)
#define BAR()                               \
  do {                                      \
    asm volatile("" ::: "memory");          \
    __builtin_amdgcn_s_barrier();           \
    asm volatile("" ::: "memory");          \
  } while (0)

// ---- NT GEMM: C[m][n] = sum_k A[m][k]*Bm[n][k] + bias[n]; A:MxK, Bm:NxK (row-major bf16) ----
// 256x256 tile, BK=64, 512 threads = 8 waves (2M x 4N), per-wave 128x64 output (acc[8][4]).
// Double-buffered LDS (2 x 64 KB), 4-balanced-phase schedule (R3; K-loop frozen — three
// schedule variants all measured MfmaUtil 27-29%, this one is the best of them).
//
// MODE 0: plain fp32 output + bias (GEMM2).
// MODE 1 (GEMM1): fused recurrence-transform epilogue. Each block owns 128 CHANNELS
//   (both halves): Bs tile rows 0..127 = Bm rows [n0, n0+128) (hidden), rows 128..255 =
//   Bm rows [1024+n0, ...) (gate), n0 = bn/2. Per-wave fragment map wn0=(wave&3)*32:
//   acc[mi][0..1] = hidden cols, acc[mi][2..3] = gate cols of the SAME channels ->
//   lane-local (hd,g) pairing. Epilogue computes lc=-softplus(g+bg),
//   v=-softplus(-(g+bg))+log_g(hd+bh) in fp32 and writes lc -> C[l][ch], v -> C[l][1024+ch]
//   (same layout/volume as writing hidden/gate; scans then skip the transform entirely).
//
// LDS swizzle (128B rows, 8x16B chunks): phys chunk p of row r holds logical chunk p^(r&7);
// staging lane (rl=lane>>3, slot=lane&7) fetches global chunk slot^rl; frag read uses
// (kh*4+quad)^(l15&7). Measured 0 bank conflicts (R0-R3).
// XCD-aware block swizzle (both grids divisible by 8). setprio(1) around MFMA clusters.
template <int MODE>
__global__ __launch_bounds__(512, 2)
void gemm_bt(const ushort* __restrict__ A, const ushort* __restrict__ Bm,
             const float* __restrict__ bias, void* __restrict__ Cv,
             int M, int N, int K) {
  __shared__ ushort As[2][256 * 64];
  __shared__ ushort Bs[2][256 * 64];
  const int tid  = threadIdx.x;
  const int wave = tid >> 6;
  const int lane = tid & 63;
  const int l15  = lane & 15;
  const int quad = lane >> 4;

  // XCD swizzle: dispatch index d goes to XCD d%8; give each XCD a contiguous logical chunk.
  int id = blockIdx.y * gridDim.x + blockIdx.x;
  const int nwg = gridDim.x * gridDim.y;
  id = (id & 7) * (nwg >> 3) + (id >> 3);
  const int bxi = id % gridDim.x;
  const int byi = id / gridDim.x;

  const long bm = (long)byi * 256;
  const long bn = (long)bxi * 256;
  const int  wm = (wave >> 2) * 128;   // 0 or 128

  f32x4 acc[8][4];
#pragma unroll
  for (int i = 0; i < 8; ++i)
#pragma unroll
    for (int j = 0; j < 4; ++j) acc[i][j] = (f32x4){0.f, 0.f, 0.f, 0.f};

  // staging: wave fills rows [wave*32, wave*32+32); each instr covers 8 rows (64 lanes x 16B).
  // Lane: rl = lane>>3 (row in 8-row group), phys slot = lane&7, global chunk = slot^rl.
  const int rl  = lane >> 3;
  const int cb  = (lane & 7) ^ rl;
  const int srow = wave * 32 + rl;
  const ushort* gA0 = A + (bm + srow) * (long)K + cb * 8;
  const ushort* gB0;
  if (MODE == 1) {
    // B-tile rows: 0..127 hidden channels [n0, n0+128), 128..255 gate [1024+n0, ...)
    const long n0 = bn >> 1;
    const long grow = (srow < 128) ? (n0 + srow) : (1024 + n0 + (srow - 128));
    gB0 = Bm + grow * (long)K + cb * 8;
  } else {
    gB0 = Bm + (bn + srow) * (long)K + cb * 8;
  }
  int ldst[4];
#pragma unroll
  for (int i = 0; i < 4; ++i) ldst[i] = (wave * 32 + 8 * i) * 64;

  // fragment-read swizzled slot offsets (ushort units): (kh*4+quad) ^ (l15&7)
  const int sq0 = ((0 * 4 + quad) ^ (l15 & 7)) * 8;
  const int sq1 = ((1 * 4 + quad) ^ (l15 & 7)) * 8;
  int arow[8], brow[4];
#pragma unroll
  for (int i = 0; i < 8; ++i) arow[i] = (wm + i * 16 + l15) * 64;
  if (MODE == 1) {
    const int wn0 = (wave & 3) * 32;   // 32 channels per wave; j<2 hidden, j>=2 gate
#pragma unroll
    for (int j = 0; j < 4; ++j) {
      const int trow = (j < 2) ? (wn0 + j * 16) : (128 + wn0 + (j - 2) * 16);
      brow[j] = (trow + l15) * 64;
    }
  } else {
    const int wn = (wave & 3) * 64;
#pragma unroll
    for (int j = 0; j < 4; ++j) brow[j] = (wn + j * 16 + l15) * 64;
  }

  const int nkt = K >> 6;

  // prologue: stage K-step 0 -> buf 0; cold drain (unavoidable once per block)
#pragma unroll
  for (int i = 0; i < 4; ++i) GLDS(gA0 + 8L * i * K, &As[0][ldst[i]]);
#pragma unroll
  for (int i = 0; i < 4; ++i) GLDS(gB0 + 8L * i * K, &Bs[0][ldst[i]]);
  asm volatile("s_waitcnt vmcnt(0)" ::: "memory");
  BAR();

  for (int t = 0; t < nkt; ++t) {
    const int buf  = t & 1;
    const int nbuf = buf ^ 1;
    const bool pf  = (t + 1) < nkt;
    const ushort* Ac = As[buf];
    const ushort* Bc = Bs[buf];
    const long koff = (long)(t + 1) * 64;
    s16x8 bf[4], af[4];

    // ---- phase 1: (mh0, kh0); stage A(t+1) ----
#pragma unroll
    for (int j = 0; j < 4; ++j)
      bf[j] = *reinterpret_cast<const s16x8*>(&Bc[brow[j] + sq0]);
#pragma unroll
    for (int i = 0; i < 4; ++i)
      af[i] = *reinterpret_cast<const s16x8*>(&Ac[arow[i] + sq0]);
    if (pf) {
      // WAR safe: buf nbuf holds K-step t-1, fully consumed before iter t-1's final barrier.
#pragma unroll
      for (int i = 0; i < 4; ++i) GLDS(gA0 + 8L * i * K + koff, &As[nbuf][ldst[i]]);
    }
    BAR();
    __builtin_amdgcn_s_setprio(1);
#pragma unroll
    for (int i = 0; i < 4; ++i)
#pragma unroll
      for (int j = 0; j < 4; ++j)
        acc[i][j] = mfma_bf16_16x16x32(af[i], bf[j], acc[i][j]);
    __builtin_amdgcn_s_setprio(0);
    BAR();

    // ---- phase 2: (mh1, kh0); stage B(t+1) ----
#pragma unroll
    for (int i = 0; i < 4; ++i)
      af[i] = *reinterpret_cast<const s16x8*>(&Ac[arow[4 + i] + sq0]);
    if (pf) {
#pragma unroll
      for (int i = 0; i < 4; ++i) GLDS(gB0 + 8L * i * K + koff, &Bs[nbuf][ldst[i]]);
    }
    BAR();
    __builtin_amdgcn_s_setprio(1);
#pragma unroll
    for (int i = 0; i < 4; ++i)
#pragma unroll
      for (int j = 0; j < 4; ++j)
        acc[4 + i][j] = mfma_bf16_16x16x32(af[i], bf[j], acc[4 + i][j]);
    __builtin_amdgcn_s_setprio(0);
    BAR();

    // ---- phase 3: (mh0, kh1) ----
#pragma unroll
    for (int j = 0; j < 4; ++j)
      bf[j] = *reinterpret_cast<const s16x8*>(&Bc[brow[j] + sq1]);
#pragma unroll
    for (int i = 0; i < 4; ++i)
      af[i] = *reinterpret_cast<const s16x8*>(&Ac[arow[i] + sq1]);
    BAR();
    __builtin_amdgcn_s_setprio(1);
#pragma unroll
    for (int i = 0; i < 4; ++i)
#pragma unroll
      for (int j = 0; j < 4; ++j)
        acc[i][j] = mfma_bf16_16x16x32(af[i], bf[j], acc[i][j]);
    __builtin_amdgcn_s_setprio(0);
    BAR();

    // ---- phase 4: (mh1, kh1); drain t+1's loads after MFMA-issue ----
#pragma unroll
    for (int i = 0; i < 4; ++i)
      af[i] = *reinterpret_cast<const s16x8*>(&Ac[arow[4 + i] + sq1]);
    BAR();
    __builtin_amdgcn_s_setprio(1);
#pragma unroll
    for (int i = 0; i < 4; ++i)
#pragma unroll
      for (int j = 0; j < 4; ++j)
        acc[4 + i][j] = mfma_bf16_16x16x32(af[i], bf[j], acc[4 + i][j]);
    __builtin_amdgcn_s_setprio(0);
    if (pf) asm volatile("s_waitcnt vmcnt(0)" ::: "memory");
    BAR();   // after this barrier, all waves' t+1 loads are visible in LDS
  }

  // epilogue: C/D layout col = lane&15, row = quad*4 + reg
  if (MODE == 1) {
    const long n0  = bn >> 1;
    const int  wn0 = (wave & 3) * 32;
#pragma unroll
    for (int mi = 0; mi < 8; ++mi) {
      const long mrow = bm + wm + mi * 16 + quad * 4;
#pragma unroll
      for (int j = 0; j < 2; ++j) {
        const long ch = n0 + wn0 + j * 16 + l15;
        const float bh = bias[ch];
        const float bg = bias[(long)(N >> 1) + ch];   // gate bias (N/2 = H)
        ushort* lp = (ushort*)Cv + mrow * (long)N + ch;
#pragma unroll
        for (int r = 0; r < 4; ++r) {
          float hd = acc[mi][j][r] + bh;
          float g  = acc[mi][j + 2][r] + bg;
          float lc, v; transform_f(hd, g, lc, v);
          lp[(long)r * N] = f2bf(lc);
          lp[(long)r * N + (N >> 1)] = f2bf(v);
        }
      }
    }
  } else {
    const int wn = (wave & 3) * 64;
#pragma unroll
    for (int mi = 0; mi < 8; ++mi) {
      const long mrow = bm + wm + mi * 16 + quad * 4;
#pragma unroll
      for (int ni = 0; ni < 4; ++ni) {
        const long ncol = bn + wn + ni * 16 + l15;
        const float bv = bias[ncol];
        float* cp = (float*)Cv + mrow * (long)N + ncol;
#pragma unroll
        for (int r = 0; r < 4; ++r) cp[(long)r * N] = acc[mi][ni][r] + bv;
      }
    }
  }
}

// phase 1: per (b, chunk, h-quad) compose chunk (Asum, Bv) for 4 channels.
// hg now holds (lc, v) precomputed by GEMM1's epilogue: lc at col ch, v at col 1024+ch.
__global__ void scan_phase1(const ushort* __restrict__ hg,
                            float* __restrict__ Ac, float* __restrict__ Bc) {
  int gid = blockIdx.x * blockDim.x + threadIdx.x;  // B_*NC_*H_/4
  int hq = gid & (H_ / 4 - 1);       // h/4, 0..255
  int c  = (gid >> 8) & (NC_ - 1);
  int b  = gid >> 16;
  const ushort* p = hg + ((size_t)(b * L_ + c * LC_) * (2 * H_)) + hq * 4;
  float As[4] = {0.f, 0.f, 0.f, 0.f};
  float Bv[4] = {-INFINITY, -INFINITY, -INFINITY, -INFINITY};
#pragma unroll 4
  for (int l = 0; l < LC_; ++l) {
    ushort4 lc4 = *reinterpret_cast<const ushort4*>(p);
    ushort4 v4  = *reinterpret_cast<const ushort4*>(p + H_);
    float lcv[4] = {bf2f(lc4.x), bf2f(lc4.y), bf2f(lc4.z), bf2f(lc4.w)};
    float vv[4]  = {bf2f(v4.x),  bf2f(v4.y),  bf2f(v4.z),  bf2f(v4.w)};
#pragma unroll
    for (int j = 0; j < 4; ++j) {
      As[j] += lcv[j];
      Bv[j] = logaddexp_f(Bv[j] + lcv[j], vv[j]);
    }
    p += 2 * H_;
  }
  size_t o = (size_t)(b * NC_ + c) * H_ + hq * 4;
  *reinterpret_cast<float4*>(&Ac[o]) = make_float4(As[0], As[1], As[2], As[3]);
  *reinterpret_cast<float4*>(&Bc[o]) = make_float4(Bv[0], Bv[1], Bv[2], Bv[3]);
}

// phase 2: per (b, h) exclusive scan over chunk summaries -> carry (incoming log_h per chunk)
__global__ void scan_phase2(const float* __restrict__ Ac, const float* __restrict__ Bc,
                            float* __restrict__ carry) {
  int gid = blockIdx.x * blockDim.x + threadIdx.x;  // B_*H_
  int h = gid & (H_ - 1);
  int b = gid >> 10;
  float P = -INFINITY;
  for (int c = 0; c < NC_; ++c) {
    size_t o = (size_t)(b * NC_ + c) * H_ + h;
    carry[o] = P;
    P = logaddexp_f(P + Ac[o], Bc[o]);
  }
}

// phase 3: re-scan chunk with carry, emit h = exp(log_h) as bf16 (4 channels/thread)
__global__ void scan_phase3(const ushort* __restrict__ hg, const float* __restrict__ carry,
                            ushort* __restrict__ hb) {
  int gid = blockIdx.x * blockDim.x + threadIdx.x;  // B_*NC_*H_/4
  int hq = gid & (H_ / 4 - 1);
  int c  = (gid >> 8) & (NC_ - 1);
  int b  = gid >> 16;
  float4 cr = *reinterpret_cast<const float4*>(&carry[(size_t)(b * NC_ + c) * H_ + hq * 4]);
  float lh[4] = {cr.x, cr.y, cr.z, cr.w};
  const ushort* p = hg + ((size_t)(b * L_ + c * LC_) * (2 * H_)) + hq * 4;
  ushort* q = hb + (size_t)(b * L_ + c * LC_) * H_ + hq * 4;
#pragma unroll 4
  for (int l = 0; l < LC_; ++l) {
    ushort4 lc4 = *reinterpret_cast<const ushort4*>(p);
    ushort4 v4  = *reinterpret_cast<const ushort4*>(p + H_);
    float lcv[4] = {bf2f(lc4.x), bf2f(lc4.y), bf2f(lc4.z), bf2f(lc4.w)};
    float vv[4]  = {bf2f(v4.x),  bf2f(v4.y),  bf2f(v4.z),  bf2f(v4.w)};
    ushort4 o;
    ushort* op = &o.x;
#pragma unroll
    for (int j = 0; j < 4; ++j) {
      lh[j] = logaddexp_f(lh[j] + lcv[j], vv[j]);
      op[j] = f2bf(__expf(lh[j]));
    }
    *reinterpret_cast<ushort4*>(q) = o;
    p += 2 * H_;
    q += H_;
  }
}

extern "C" void kernel_launch(void* const* d_in, const int* in_sizes, int n_in,
                              void* d_out, int out_size, void* d_ws, size_t ws_size,
                              hipStream_t stream) {
  const float* x     = (const float*)d_in[0];
  const float* W_in  = (const float*)d_in[1];
  const float* b_in  = (const float*)d_in[2];
  const float* W_out = (const float*)d_in[3];
  const float* b_out = (const float*)d_in[4];
  float* out = (float*)d_out;

  char* ws = (char*)d_ws;
  size_t off = 0;
  auto alloc = [&](size_t bytes) {
    void* p = ws + off;
    off = (off + bytes + 255) & ~(size_t)255;
    return p;
  };
  // region shared by xb (alive: cast -> GEMM1) and hb (alive: phase3 -> GEMM2)
  ushort* xb    = (ushort*)alloc((size_t)B_ * L_ * H_ * 2);       // 67 MB (union)
  ushort* hb    = xb;
  ushort* Wib   = (ushort*)alloc((size_t)2 * H_ * D_ * 2);        // 2 MB
  ushort* Wob   = (ushort*)alloc((size_t)D_ * H_ * 2);            // 1 MB
  ushort* hgb   = (ushort*)alloc((size_t)B_ * L_ * 2 * H_ * 2);   // 134 MB (bf16: lc, v)
  float*  Ac    = (float*)alloc((size_t)B_ * NC_ * H_ * 4);       // 4 MB
  float*  Bc    = (float*)alloc((size_t)B_ * NC_ * H_ * 4);       // 4 MB
  float*  carry = (float*)alloc((size_t)B_ * NC_ * H_ * 4);       // 4 MB
  // total ~216 MB

  // casts to bf16
  cast_kernel<<<(B_ * L_ * D_ / 4 + 255) / 256, 256, 0, stream>>>(x, xb, B_ * L_ * D_ / 4);
  {
    int n0 = 2 * H_ * D_ / 4, n1 = D_ * H_ / 4;
    cast2_kernel<<<(n0 + n1 + 255) / 256, 256, 0, stream>>>(W_in, Wib, n0, W_out, Wob, n1);
  }

  // GEMM1: (lc, v) = transform(x . W_in^T + b_in)   (M=32768, N=2048, K=512), bf16 out
  gemm_bt<1><<<dim3((2 * H_) / 256, (B_ * L_) / 256), 512, 0, stream>>>(
      xb, Wib, b_in, hgb, B_ * L_, 2 * H_, D_);

  // chunked scan along L (4 channels per thread)
  scan_phase1<<<(B_ * NC_ * H_ / 4) / 256, 256, 0, stream>>>(hgb, Ac, Bc);
  scan_phase2<<<(B_ * H_) / 256, 256, 0, stream>>>(Ac, Bc, carry);
  scan_phase3<<<(B_ * NC_ * H_ / 4) / 256, 256, 0, stream>>>(hgb, carry, hb);

  // GEMM2: out = h . W_out^T + b_out   (M=32768, N=512, K=1024), fp32 out
  gemm_bt<0><<<dim3(D_ / 256, (B_ * L_) / 256), 512, 0, stream>>>(
      hb, Wob, b_out, out, B_ * L_, D_, H_);
}